// Round 5
// baseline (1361.228 us; speedup 1.0000x reference)
//
#include <hip/hip_runtime.h>
#include <math.h>

#define Bq 4
#define Tt 2048
#define Dd 512
#define Hh 8
#define Ll 4
#define HIDN 2048
#define DHd 64
#define BT (Bq*Tt)                 // 8192
#define BTD ((size_t)BT*Dd)        // 4194304

typedef __attribute__((ext_vector_type(8))) __bf16 bf16x8;
typedef __attribute__((ext_vector_type(4))) __bf16 bf16x4;
typedef __attribute__((ext_vector_type(2))) __bf16 bf16x2;
typedef __attribute__((ext_vector_type(4))) float f32x4;

static __device__ __forceinline__ int is_sep(int t) {
    const unsigned long long w0 = 0xFC00FFFF00002600ULL;
    const unsigned long long w1 = 0x7800000078000001ULL;
    if (t < 64)  return (int)((w0 >> t) & 1ULL);
    if (t < 128) return (int)((w1 >> (t - 64)) & 1ULL);
    return 0;
}

static __device__ __forceinline__ void gload16(const void* g, void* l) {
    __builtin_amdgcn_global_load_lds(
        (const __attribute__((address_space(1))) void*)g,
        (__attribute__((address_space(3))) void*)l, 16, 0, 0);
}

__global__ void embed_kernel(const int* __restrict__ tokens, const float* __restrict__ embed,
                             float* __restrict__ x) {
    size_t idx = (size_t)blockIdx.x * blockDim.x + threadIdx.x;
    if (idx >= BTD / 4) return;
    size_t row = idx >> 7;
    int tk = tokens[row];
    tk = tk < 0 ? 0 : (tk > 255 ? 255 : tk);
    const float4* src = (const float4*)(embed + (size_t)tk * Dd);
    ((float4*)x)[idx] = src[idx & 127];
}

__global__ void rope_table_kernel(float* __restrict__ cosb, float* __restrict__ sinb) {
    int idx = blockIdx.x * blockDim.x + threadIdx.x;
    if (idx >= Tt * 32) return;
    int t = idx >> 5, j = idx & 31;
    float inv = powf(10000.0f, -(2.0f * j) / 64.0f);
    float ang = (float)t * inv;
    cosb[idx] = cosf(ang);
    sinb[idx] = sinf(ang);
}

__global__ void cvt_bf16_kernel(const float* __restrict__ in, __bf16* __restrict__ out, int n8) {
    int i = blockIdx.x * blockDim.x + threadIdx.x;
    if (i >= n8) return;
    const float4* p = (const float4*)(in + (size_t)i * 8);
    float4 a = p[0], b = p[1];
    bf16x8 o8;
    o8[0] = (__bf16)a.x; o8[1] = (__bf16)a.y; o8[2] = (__bf16)a.z; o8[3] = (__bf16)a.w;
    o8[4] = (__bf16)b.x; o8[5] = (__bf16)b.y; o8[6] = (__bf16)b.z; o8[7] = (__bf16)b.w;
    *(bf16x8*)(out + (size_t)i * 8) = o8;
}

// concat wq/wk/wv -> wqkv[L][1536][512] bf16
__global__ void cvt_qkv_kernel(const float* __restrict__ wq, const float* __restrict__ wk,
                               const float* __restrict__ wv, __bf16* __restrict__ out) {
    int i = blockIdx.x * blockDim.x + threadIdx.x;   // 393216
    if (i >= 393216) return;
    int l = i / 98304;
    int r = i - l * 98304;
    int t = r >> 15;             // /32768
    int pos8 = r & 32767;
    const float* src = (t == 0 ? wq : (t == 1 ? wk : wv)) + (size_t)l * 262144 + (size_t)pos8 * 8;
    float4 a = *(const float4*)src;
    float4 b = *(const float4*)(src + 4);
    bf16x8 o8;
    o8[0] = (__bf16)a.x; o8[1] = (__bf16)a.y; o8[2] = (__bf16)a.z; o8[3] = (__bf16)a.w;
    o8[4] = (__bf16)b.x; o8[5] = (__bf16)b.y; o8[6] = (__bf16)b.z; o8[7] = (__bf16)b.w;
    *(bf16x8*)(out + (size_t)i * 8) = o8;
}

// fp32 in, fp32 out (final norm)
__global__ void rmsnorm_kernel(const float* __restrict__ x, const float* __restrict__ w,
                               float* __restrict__ y) {
    int row = blockIdx.x;
    int tid = threadIdx.x;
    const float2* xr = (const float2*)(x + (size_t)row * Dd);
    float2 v = xr[tid];
    __shared__ float red[256];
    red[tid] = v.x * v.x + v.y * v.y;
    __syncthreads();
    for (int off = 128; off > 0; off >>= 1) {
        if (tid < off) red[tid] += red[tid + off];
        __syncthreads();
    }
    float scale = rsqrtf(red[0] * (1.0f / Dd) + 1e-6f);
    float2 wv = ((const float2*)w)[tid];
    ((float2*)(y + (size_t)row * Dd))[tid] = make_float2(v.x * scale * wv.x, v.y * scale * wv.y);
}

// fp32 in, bf16 out
__global__ void rmsnorm_bf16_kernel(const float* __restrict__ x, const float* __restrict__ w,
                                    __bf16* __restrict__ y) {
    int row = blockIdx.x;
    int tid = threadIdx.x;
    const float2* xr = (const float2*)(x + (size_t)row * Dd);
    float2 v = xr[tid];
    __shared__ float red[256];
    red[tid] = v.x * v.x + v.y * v.y;
    __syncthreads();
    for (int off = 128; off > 0; off >>= 1) {
        if (tid < off) red[tid] += red[tid + off];
        __syncthreads();
    }
    float scale = rsqrtf(red[0] * (1.0f / Dd) + 1e-6f);
    float2 wv = ((const float2*)w)[tid];
    bf16x2 o;
    o[0] = (__bf16)(v.x * scale * wv.x);
    o[1] = (__bf16)(v.y * scale * wv.y);
    *(bf16x2*)(y + (size_t)row * Dd + 2 * tid) = o;
}

// C = A(bf16) @ Bw(bf16)^T [+ res(f32)]. 128x128 tile, BK=32, double-buffered gload_lds.
// EPI 0: bf16 out stride N. EPI 1: f32 out + f32 residual. EPI 2: bf16 QKV split
// (Cout = q base; q/k/v contiguous BTD apart; dst col = col&511, buffer = col>>9).
template<int EPI>
__global__ __launch_bounds__(256) void gemm_bt_mfma(
    const __bf16* __restrict__ A, const __bf16* __restrict__ Bw,
    const float* __restrict__ res, void* __restrict__ Cout,
    int N, int K) {
    __shared__ __align__(16) __bf16 lds[2][2][128 * 32];
    const int tid = threadIdx.x;
    const int w = tid >> 6, lane = tid & 63;
    const int l15 = lane & 15, g4 = lane >> 4;
    const int wr = w >> 1, wc = w & 1;
    const int bm = blockIdx.y * 128, bn = blockIdx.x * 128;
    const int lrow = lane >> 2, lc8 = (lane & 3) * 8;
    const int chunk0 = w * 2;

    f32x4 acc[4][4];
    #pragma unroll
    for (int m = 0; m < 4; m++)
        #pragma unroll
        for (int n = 0; n < 4; n++) acc[m][n] = (f32x4){0.f, 0.f, 0.f, 0.f};

    auto stage = [&](int buf, int k0) {
        #pragma unroll
        for (int c = 0; c < 2; c++) {
            int chunk = chunk0 + c;
            const __bf16* ga = A + (size_t)(bm + chunk * 16 + lrow) * K + k0 + lc8;
            gload16(ga, &lds[buf][0][chunk * 512]);
            const __bf16* gb = Bw + (size_t)(bn + chunk * 16 + lrow) * K + k0 + lc8;
            gload16(gb, &lds[buf][1][chunk * 512]);
        }
    };

    stage(0, 0);
    __syncthreads();
    const int NT = K >> 5;
    int cur = 0;
    for (int t = 0; t < NT; t++) {
        if (t + 1 < NT) stage(cur ^ 1, (t + 1) << 5);
        const __bf16* Al = &lds[cur][0][0];
        const __bf16* Bl = &lds[cur][1][0];
        bf16x8 af[4], bfr[4];
        #pragma unroll
        for (int m = 0; m < 4; m++)
            af[m] = *(const bf16x8*)&Al[(wr * 64 + m * 16 + l15) * 32 + g4 * 8];
        #pragma unroll
        for (int n = 0; n < 4; n++)
            bfr[n] = *(const bf16x8*)&Bl[(wc * 64 + n * 16 + l15) * 32 + g4 * 8];
        #pragma unroll
        for (int m = 0; m < 4; m++)
            #pragma unroll
            for (int n = 0; n < 4; n++)
                acc[m][n] = __builtin_amdgcn_mfma_f32_16x16x32_bf16(af[m], bfr[n], acc[m][n], 0, 0, 0);
        __syncthreads();
        cur ^= 1;
    }

    #pragma unroll
    for (int m = 0; m < 4; m++)
        #pragma unroll
        for (int n = 0; n < 4; n++)
            #pragma unroll
            for (int r = 0; r < 4; r++) {
                size_t row = bm + wr * 64 + m * 16 + g4 * 4 + r;
                int col = bn + wc * 64 + n * 16 + l15;
                if (EPI == 0) {
                    ((__bf16*)Cout)[row * N + col] = (__bf16)acc[m][n][r];
                } else if (EPI == 1) {
                    ((float*)Cout)[row * N + col] = acc[m][n][r] + res[row * N + col];
                } else {
                    ((__bf16*)Cout)[(size_t)(col >> 9) * BTD + row * 512 + (col & 511)] =
                        (__bf16)acc[m][n][r];
                }
            }
}

// G = silu(A@W1^T) * (A@W3^T), bf16 out.
__global__ __launch_bounds__(256) void gemm_swiglu_mfma(
    const __bf16* __restrict__ A, const __bf16* __restrict__ W1,
    const __bf16* __restrict__ W3, __bf16* __restrict__ G,
    int N, int K) {
    __shared__ __align__(16) __bf16 lds[2][3][128 * 32];
    const int tid = threadIdx.x;
    const int w = tid >> 6, lane = tid & 63;
    const int l15 = lane & 15, g4 = lane >> 4;
    const int wr = w >> 1, wc = w & 1;
    const int bm = blockIdx.y * 128, bn = blockIdx.x * 128;
    const int lrow = lane >> 2, lc8 = (lane & 3) * 8;
    const int chunk0 = w * 2;

    f32x4 acc1[4][4], acc3[4][4];
    #pragma unroll
    for (int m = 0; m < 4; m++)
        #pragma unroll
        for (int n = 0; n < 4; n++) {
            acc1[m][n] = (f32x4){0.f, 0.f, 0.f, 0.f};
            acc3[m][n] = (f32x4){0.f, 0.f, 0.f, 0.f};
        }

    auto stage = [&](int buf, int k0) {
        #pragma unroll
        for (int c = 0; c < 2; c++) {
            int chunk = chunk0 + c;
            const __bf16* ga = A + (size_t)(bm + chunk * 16 + lrow) * K + k0 + lc8;
            gload16(ga, &lds[buf][0][chunk * 512]);
            const __bf16* g1 = W1 + (size_t)(bn + chunk * 16 + lrow) * K + k0 + lc8;
            gload16(g1, &lds[buf][1][chunk * 512]);
            const __bf16* g3 = W3 + (size_t)(bn + chunk * 16 + lrow) * K + k0 + lc8;
            gload16(g3, &lds[buf][2][chunk * 512]);
        }
    };

    stage(0, 0);
    __syncthreads();
    const int NT = K >> 5;
    int cur = 0;
    for (int t = 0; t < NT; t++) {
        if (t + 1 < NT) stage(cur ^ 1, (t + 1) << 5);
        const __bf16* Al = &lds[cur][0][0];
        const __bf16* B1 = &lds[cur][1][0];
        const __bf16* B3 = &lds[cur][2][0];
        bf16x8 af[4];
        #pragma unroll
        for (int m = 0; m < 4; m++)
            af[m] = *(const bf16x8*)&Al[(wr * 64 + m * 16 + l15) * 32 + g4 * 8];
        #pragma unroll
        for (int n = 0; n < 4; n++) {
            bf16x8 b1 = *(const bf16x8*)&B1[(wc * 64 + n * 16 + l15) * 32 + g4 * 8];
            bf16x8 b3 = *(const bf16x8*)&B3[(wc * 64 + n * 16 + l15) * 32 + g4 * 8];
            #pragma unroll
            for (int m = 0; m < 4; m++) {
                acc1[m][n] = __builtin_amdgcn_mfma_f32_16x16x32_bf16(af[m], b1, acc1[m][n], 0, 0, 0);
                acc3[m][n] = __builtin_amdgcn_mfma_f32_16x16x32_bf16(af[m], b3, acc3[m][n], 0, 0, 0);
            }
        }
        __syncthreads();
        cur ^= 1;
    }

    #pragma unroll
    for (int m = 0; m < 4; m++)
        #pragma unroll
        for (int n = 0; n < 4; n++)
            #pragma unroll
            for (int r = 0; r < 4; r++) {
                size_t row = bm + wr * 64 + m * 16 + g4 * 4 + r;
                size_t col = bn + wc * 64 + n * 16 + l15;
                float a1 = acc1[m][n][r];
                float sig = 1.0f / (1.0f + __expf(-a1));
                G[row * N + col] = (__bf16)(a1 * sig * acc3[m][n][r]);
            }
}

// RoPE over q (scaled by 0.125*log2e, for exp2-domain softmax) and k, one kernel.
__global__ void rope2_kernel(__bf16* __restrict__ qb, __bf16* __restrict__ kb,
                             const float* __restrict__ cosb, const float* __restrict__ sinb) {
    int idx = blockIdx.x * blockDim.x + threadIdx.x;   // 2*BT*64
    if (idx >= 2 * BT * 64) return;
    int which = idx >= BT * 64;                        // 0=q, 1=k (uniform per block)
    int idq = idx & (BT * 64 - 1);
    __bf16* buf = which ? kb : qb;
    float scale = which ? 1.0f : 0.18033688011112043f; // 0.125 * log2(e)
    int row = idq >> 6, seg = idq & 63;
    int t = row & (Tt - 1);
    int j4 = (seg & 7) * 4;
    bf16x8 v = *(bf16x8*)(buf + (size_t)row * Dd + seg * 8);
    float4 c4 = *(const float4*)(cosb + (t << 5) + j4);
    float4 s4 = *(const float4*)(sinb + (t << 5) + j4);
    const float* cp = (const float*)&c4;
    const float* sp = (const float*)&s4;
    bf16x8 o;
    #pragma unroll
    for (int p = 0; p < 4; p++) {
        float a = (float)v[2 * p], b = (float)v[2 * p + 1];
        o[2 * p]     = (__bf16)((a * cp[p] - b * sp[p]) * scale);
        o[2 * p + 1] = (__bf16)((a * sp[p] + b * cp[p]) * scale);
    }
    *(bf16x8*)(buf + (size_t)row * Dd + seg * 8) = o;
}

// Flash attention: 4 waves x 16 q-rows, KVBLK=128.
// K: async global_load_lds into linear Ks[128][64], both-sides XOR swizzle
//    (slot ^= row&7 on the 16B slot index; source column pre-swizzled).
// V: reg-staged transposed Vt[64][128] with slot ^= d&15 swizzle -> b128 B-frag reads.
// Softmax in exp2 domain (q pre-scaled by 0.125*log2e).
__global__ __launch_bounds__(256) void attn_mfma_kernel(
    const __bf16* __restrict__ q, const __bf16* __restrict__ k,
    const __bf16* __restrict__ v, __bf16* __restrict__ o) {
    __shared__ __align__(16) __bf16 KsF[128 * 64];
    __shared__ __align__(16) __bf16 VtF[64 * 128];
    __shared__ __align__(16) __bf16 PsF[4][16][136];

    int tid = threadIdx.x;
    int w = tid >> 6;
    int lane = tid & 63;
    int l15 = lane & 15;
    int g = lane >> 4;
    int bh = blockIdx.y;
    int b = bh >> 3, h = bh & 7;
    int qbase = blockIdx.x * 64;

    const __bf16* qp = q + (size_t)b * Tt * Dd + (size_t)h * DHd;
    const __bf16* kp = k + (size_t)b * Tt * Dd + (size_t)h * DHd;
    const __bf16* vp = v + (size_t)b * Tt * Dd + (size_t)h * DHd;

    bf16x8 qa[2];
    {
        const __bf16* qrow = qp + (size_t)(qbase + w * 16 + l15) * Dd;
        qa[0] = *(const bf16x8*)(qrow + g * 8);
        qa[1] = *(const bf16x8*)(qrow + 32 + g * 8);
    }

    f32x4 oacc[4];
    #pragma unroll
    for (int i = 0; i < 4; i++) oacc[i] = (f32x4){0.f, 0.f, 0.f, 0.f};
    float mrun[4] = {-1e30f, -1e30f, -1e30f, -1e30f};
    float lrun[4] = {0.f, 0.f, 0.f, 0.f};

    for (int t = 0; t < Tt / 128; t++) {
        int kv0 = t * 128;
        __syncthreads();
        // K tile: 4 async DMA rounds, dest lane-linear, source col pre-swizzled
        #pragma unroll
        for (int r = 0; r < 4; r++) {
            int row = r * 32 + (tid >> 3);
            int srccol = (((tid & 7) ^ (row & 7)) << 3);
            gload16(kp + (size_t)(kv0 + row) * Dd + srccol, &KsF[(size_t)row * 64 + ((tid & 7) << 3)]);
        }
        // V tile: reg-staged transpose with 4-bit slot swizzle
        #pragma unroll
        for (int p = 0; p < 4; p++) {
            int f = p * 256 + tid;
            int s = f >> 3, c8 = (f & 7) * 8;
            bf16x8 vv = *(const bf16x8*)(vp + (size_t)(kv0 + s) * Dd + c8);
            #pragma unroll
            for (int j = 0; j < 8; j++) {
                int d = c8 + j;
                VtF[d * 128 + ((((s >> 3) ^ d) & 15) << 3) + (s & 7)] = vv[j];
            }
        }
        __syncthreads();

        // QK^T: S[16 q][128 kv], swizzled Ks reads
        f32x4 s4[8];
        #pragma unroll
        for (int c = 0; c < 8; c++) {
            int row = c * 16 + l15;
            int sw = row & 7;
            s4[c] = (f32x4){0.f, 0.f, 0.f, 0.f};
            bf16x8 kb0 = *(const bf16x8*)&KsF[row * 64 + ((g ^ sw) << 3)];
            s4[c] = __builtin_amdgcn_mfma_f32_16x16x32_bf16(qa[0], kb0, s4[c], 0, 0, 0);
            bf16x8 kb1 = *(const bf16x8*)&KsF[row * 64 + (((4 + g) ^ sw) << 3)];
            s4[c] = __builtin_amdgcn_mfma_f32_16x16x32_bf16(qa[1], kb1, s4[c], 0, 0, 0);
        }

        // online softmax, exp2 domain
        float tmax[4], alpha[4], psum[4];
        #pragma unroll
        for (int r = 0; r < 4; r++) {
            float tm = s4[0][r];
            #pragma unroll
            for (int c = 1; c < 8; c++) tm = fmaxf(tm, s4[c][r]);
            #pragma unroll
            for (int off = 1; off < 16; off <<= 1)
                tm = fmaxf(tm, __shfl_xor(tm, off));
            float mnew = fmaxf(mrun[r], tm);
            alpha[r] = exp2f(mrun[r] - mnew);
            mrun[r] = mnew;
            psum[r] = 0.f;
        }
        #pragma unroll
        for (int c = 0; c < 8; c++)
            #pragma unroll
            for (int r = 0; r < 4; r++) {
                float e = exp2f(s4[c][r] - mrun[r]);
                s4[c][r] = e;
                psum[r] += e;
            }
        #pragma unroll
        for (int r = 0; r < 4; r++) {
            #pragma unroll
            for (int off = 1; off < 16; off <<= 1)
                psum[r] += __shfl_xor(psum[r], off);
            lrun[r] = lrun[r] * alpha[r] + psum[r];
        }
        #pragma unroll
        for (int d2 = 0; d2 < 4; d2++)
            #pragma unroll
            for (int r = 0; r < 4; r++) oacc[d2][r] *= alpha[r];
        // P -> per-wave LDS (no barrier: PsF tile is wave-private)
        #pragma unroll
        for (int c = 0; c < 8; c++)
            #pragma unroll
            for (int r = 0; r < 4; r++)
                PsF[w][g * 4 + r][c * 16 + l15] = (__bf16)s4[c][r];

        // PV: A from PsF, B from swizzled VtF (vector b128 reads)
        #pragma unroll
        for (int kc = 0; kc < 4; kc++) {
            bf16x8 pa = *(const bf16x8*)&PsF[w][l15][kc * 32 + g * 8];
            #pragma unroll
            for (int d2 = 0; d2 < 4; d2++) {
                int d = d2 * 16 + l15;
                bf16x8 vb = *(const bf16x8*)&VtF[d * 128 + ((((kc * 4 + g) ^ l15) & 15) << 3)];
                oacc[d2] = __builtin_amdgcn_mfma_f32_16x16x32_bf16(pa, vb, oacc[d2], 0, 0, 0);
            }
        }
    }

    __bf16* op = o + (size_t)b * Tt * Dd + (size_t)h * DHd;
    #pragma unroll
    for (int d2 = 0; d2 < 4; d2++)
        #pragma unroll
        for (int r = 0; r < 4; r++)
            op[(size_t)(qbase + w * 16 + g * 4 + r) * Dd + d2 * 16 + l15] =
                (__bf16)(oacc[d2][r] / lrun[r]);
}

__global__ void seg_scan_kernel(const int* __restrict__ tokens, int* __restrict__ segid) {
    int b = blockIdx.x;
    int tid = threadIdx.x;
    const int* trow = tokens + (size_t)b * Tt;
    int base = tid * 8;
    int inc[8];
    int run = 0;
    #pragma unroll
    for (int i = 0; i < 8; i++) {
        int tk = trow[base + i];
        tk = tk < 0 ? 0 : (tk > 255 ? 255 : tk);
        run += is_sep(tk);
        inc[i] = run;
    }
    __shared__ int part[256];
    part[tid] = run;
    __syncthreads();
    for (int off = 1; off < 256; off <<= 1) {
        int vv = (tid >= off) ? part[tid - off] : 0;
        __syncthreads();
        part[tid] += vv;
        __syncthreads();
    }
    int exc = part[tid] - run;
    #pragma unroll
    for (int i = 0; i < 8; i++)
        segid[(size_t)b * Tt + base + i] = exc + inc[i] + b * (Tt + 1);
}

__global__ void seg_cnt_kernel(const int* __restrict__ segid, float* __restrict__ cnt) {
    int i = blockIdx.x * blockDim.x + threadIdx.x;
    if (i < BT) atomicAdd(&cnt[segid[i]], 1.0f);
}

__global__ void seg_accum_kernel(const float* __restrict__ h, const int* __restrict__ segid,
                                 float* __restrict__ segsum) {
    size_t idx = (size_t)blockIdx.x * blockDim.x + threadIdx.x;
    if (idx >= BTD) return;
    size_t row = idx >> 9;
    int d = idx & 511;
    atomicAdd(&segsum[(size_t)segid[row] * Dd + d], h[idx]);
}

__global__ void seg_final_kernel(const float* __restrict__ h, const float* __restrict__ segsum,
                                 const float* __restrict__ cnt, const int* __restrict__ segid,
                                 float* __restrict__ out) {
    size_t idx = (size_t)blockIdx.x * blockDim.x + threadIdx.x;
    if (idx >= BTD) return;
    size_t row = idx >> 9;
    int d = idx & 511;
    int s = segid[row];
    float mean = segsum[(size_t)s * Dd + d] / fmaxf(cnt[s], 1.0f);
    out[idx] = 0.5f * h[idx] + 0.5f * mean;
}

extern "C" void kernel_launch(void* const* d_in, const int* in_sizes, int n_in,
                              void* d_out, int out_size, void* d_ws, size_t ws_size,
                              hipStream_t stream) {
    const int*   tokens       = (const int*)d_in[0];
    const float* embedw       = (const float*)d_in[1];
    const float* attn_norm_w  = (const float*)d_in[2];
    const float* wq           = (const float*)d_in[3];
    const float* wk           = (const float*)d_in[4];
    const float* wv           = (const float*)d_in[5];
    const float* wo           = (const float*)d_in[6];
    const float* ffn_norm_w   = (const float*)d_in[7];
    const float* w1           = (const float*)d_in[8];
    const float* w2           = (const float*)d_in[9];
    const float* w3           = (const float*)d_in[10];
    const float* final_norm_w = (const float*)d_in[11];
    float* out = (float*)d_out;
    float* ws  = (float*)d_ws;

    float*  x    = ws;
    __bf16* qkvo = (__bf16*)(ws + BTD);
    __bf16* qb   = qkvo;
    __bf16* kb   = qkvo + BTD;
    __bf16* vb   = qkvo + 2 * BTD;
    __bf16* obuf = qkvo + 3 * BTD;
    __bf16* gbuf = qkvo;                    // overlay (FFN phase)
    float*  segsum = ws;                    // overlay (x dead after final rmsnorm)
    float*  hfin   = ws + 2 * BTD;          // final norm out (fp32)
    __bf16* xnb  = (__bf16*)(ws + 3 * BTD);
    __bf16* wb   = (__bf16*)(ws + 3 * BTD + BTD / 2);
    float*  cosb = ws + 3 * BTD + BTD / 2 + 8388608;
    float*  sinb = cosb + (size_t)Tt * 32;
    float*  segcnt = sinb + (size_t)Tt * 32;
    int*    segid  = (int*)(segcnt + Bq * (Tt + 1));

    __bf16* wqkvb = wb;                     // [L][1536][512]
    __bf16* wob = wb + 3145728;
    __bf16* w1b = wb + 4194304;
    __bf16* w3b = wb + 8388608;
    __bf16* w2b = wb + 12582912;

    cvt_qkv_kernel<<<1536, 256, 0, stream>>>(wq, wk, wv, wqkvb);
    cvt_bf16_kernel<<<512, 256, 0, stream>>>(wo, wob, 131072);
    cvt_bf16_kernel<<<2048, 256, 0, stream>>>(w1, w1b, 524288);
    cvt_bf16_kernel<<<2048, 256, 0, stream>>>(w3, w3b, 524288);
    cvt_bf16_kernel<<<2048, 256, 0, stream>>>(w2, w2b, 524288);

    embed_kernel<<<(int)((BTD / 4 + 255) / 256), 256, 0, stream>>>(tokens, embedw, x);
    rope_table_kernel<<<(Tt * 32 + 255) / 256, 256, 0, stream>>>(cosb, sinb);

    dim3 gqkv(12, 64);   // N=1536
    dim3 gq(4, 64);      // N=512
    dim3 gs(16, 64);     // N=2048
    dim3 ga(Tt / 64, Bq * Hh);

    for (int l = 0; l < Ll; l++) {
        size_t oDD = (size_t)l * Dd * Dd;
        size_t oHD = (size_t)l * HIDN * Dd;
        rmsnorm_bf16_kernel<<<BT, 256, 0, stream>>>(x, attn_norm_w + (size_t)l * Dd, xnb);
        gemm_bt_mfma<2><<<gqkv, 256, 0, stream>>>(xnb, wqkvb + (size_t)l * 786432, nullptr, qb, 1536, Dd);
        rope2_kernel<<<4096, 256, 0, stream>>>(qb, kb, cosb, sinb);
        attn_mfma_kernel<<<ga, 256, 0, stream>>>(qb, kb, vb, obuf);
        gemm_bt_mfma<1><<<gq, 256, 0, stream>>>(obuf, wob + oDD, x, x, Dd, Dd);
        rmsnorm_bf16_kernel<<<BT, 256, 0, stream>>>(x, ffn_norm_w + (size_t)l * Dd, xnb);
        gemm_swiglu_mfma<<<gs, 256, 0, stream>>>(xnb, w1b + oHD, w3b + oHD, gbuf, HIDN, Dd);
        gemm_bt_mfma<1><<<gq, 256, 0, stream>>>(gbuf, w2b + oHD, x, x, Dd, HIDN);
    }

    rmsnorm_kernel<<<BT, 256, 0, stream>>>(x, final_norm_w, hfin);

    hipMemsetAsync(segsum, 0, (size_t)Bq * (Tt + 1) * Dd * sizeof(float), stream);
    hipMemsetAsync(segcnt, 0, (size_t)Bq * (Tt + 1) * sizeof(float), stream);
    seg_scan_kernel<<<Bq, 256, 0, stream>>>(tokens, segid);
    seg_cnt_kernel<<<(BT + 255) / 256, 256, 0, stream>>>(segid, segcnt);
    seg_accum_kernel<<<(int)((BTD + 255) / 256), 256, 0, stream>>>(hfin, segid, segsum);
    seg_final_kernel<<<(int)((BTD + 255) / 256), 256, 0, stream>>>(hfin, segsum, segcnt, segid, out);
}